// Round 5
// baseline (466.137 us; speedup 1.0000x reference)
//
#include <hip/hip_runtime.h>
#include <math.h>

#define NB   16
#define NPTS 2048
#define KNBR 20
#define NCH  16           // knn chunks per query (pass A)
#define CHSZ (NPTS/NCH)   // 128
#define IDXSP 8           // idxfeat splits
#define IDXSZ (NPTS/IDXSP)
#define NROWS (NB*NPTS)          // 32768
#define CONV_M ((double)(NB)*(double)(NPTS)*(double)(KNBR))
#define ROW_M  ((double)NROWS)
#define BN_EPS 1e-5
#define LSLOPE 0.2f

__device__ __forceinline__ float lrelu(float v) { return v >= 0.f ? v : LSLOPE * v; }

// candidate staging: (2x, 2y, 2z, -|p|^2)   query: (x, y, z, -|q|^2)
__device__ __forceinline__ float4 stage4(float px, float py, float pz)
{
    return make_float4(px + px, py + py, pz + pz,
                       -fmaf(px, px, fmaf(py, py, pz * pz)));
}

// d = 2<q,c> - |q|^2 - |c|^2, identical op order in every knn kernel
__device__ __forceinline__ float dist_eval(float4 q, float4 c)
{
    float t = fmaf(c.x, q.x, fmaf(c.y, q.y, fmaf(c.z, q.z, q.w)));
    return t + c.w;
}

// pair-insert of sorted (t0 >= t1) into sorted-desc bestv[20]
__device__ __forceinline__ void pair_insert_sorted(float (&bestv)[KNBR], float t0, float t1)
{
#pragma unroll
    for (int j = 0; j < KNBR; ++j) {
        float bj = bestv[j];
        float nb  = fmaxf(bj, t0);
        float nt0 = __builtin_amdgcn_fmed3f(bj, t0, t1);
        float nt1 = fminf(bj, t1);
        bestv[j] = nb;
        t0 = nt0; t1 = nt1;
    }
}

// ---------------------------------------------------------------------------
// KNN pass A: per (query, chunk-of-128) thread, exact top-20 values of chunk.
// ---------------------------------------------------------------------------
__global__ __launch_bounds__(256) void knn_part(const float* __restrict__ x,
                                                float* __restrict__ P)
{
    __shared__ float4 cpt[CHSZ];
    __shared__ float4 qpt[256];
    const int b  = blockIdx.x >> 7;
    const int qg = (blockIdx.x >> 4) & 7;
    const int c  = blockIdx.x & 15;
    const float* xb = x + (size_t)b * NPTS * 3;
    if (threadIdx.x < CHSZ) {
        int j = c * CHSZ + threadIdx.x;
        cpt[threadIdx.x] = stage4(xb[j*3+0], xb[j*3+1], xb[j*3+2]);
    }
    {
        int n = qg * 256 + threadIdx.x;
        float px = xb[n*3+0], py = xb[n*3+1], pz = xb[n*3+2];
        qpt[threadIdx.x] = make_float4(px, py, pz,
                                       -fmaf(px, px, fmaf(py, py, pz * pz)));
    }
    __syncthreads();
    const float4 q = qpt[threadIdx.x];
    float bestv[KNBR];
#pragma unroll
    for (int j = 0; j < KNBR; ++j) bestv[j] = -__builtin_inff();
    for (int m = 0; m < CHSZ; m += 2) {
        float d0 = dist_eval(q, cpt[m]);
        float d1 = dist_eval(q, cpt[m+1]);
        float t0 = fmaxf(d0, d1), t1 = fminf(d0, d1);
        if (__any(t0 > bestv[KNBR-1]))
            pair_insert_sorted(bestv, t0, t1);
    }
    const size_t bq = (size_t)b * NPTS + qg * 256 + threadIdx.x;
#pragma unroll
    for (int i = 0; i < KNBR; ++i)
        P[(size_t)(c * KNBR + i) * NROWS + bq] = bestv[i];
}

// ---------------------------------------------------------------------------
// KNN pass B: merge 16 sorted top-20 lists per query -> exact 20th-largest
// ---------------------------------------------------------------------------
__global__ __launch_bounds__(256) void knn_merge(const float* __restrict__ P,
                                                 float* __restrict__ thresh)
{
    const size_t bq = (size_t)blockIdx.x * 256 + threadIdx.x;
    float bestv[KNBR];
#pragma unroll
    for (int j = 0; j < KNBR; ++j) bestv[j] = -__builtin_inff();
    for (int c = 0; c < NCH; ++c)
#pragma unroll
        for (int i = 0; i < KNBR; i += 2) {
            float d0 = P[(size_t)(c * KNBR + i)     * NROWS + bq];  // d0 >= d1
            float d1 = P[(size_t)(c * KNBR + i + 1) * NROWS + bq];
            if (__any(d0 > bestv[KNBR-1]))
                pair_insert_sorted(bestv, d0, d1);
        }
    thresh[bq] = bestv[KNBR-1];
}

// ---------------------------------------------------------------------------
// Fused index recovery + edge-conv. Block = (b, 32 queries).
// Phase A: (qi, sp) threads recover indices into LDS (tie-exact, ascending m).
// Phase B: wave-per-64-channels edge conv, gathers from LDS pts.
// ---------------------------------------------------------------------------
__global__ __launch_bounds__(256) void idxfeat_kernel(const float* __restrict__ x,
        const float* __restrict__ thresh, const float* __restrict__ conv_w,
        float* __restrict__ maxh, float* __restrict__ minh, double* __restrict__ S)
{
    __shared__ float4 pts[NPTS];                       // 32 KB (2x,2y,2z,-xx)
    __shared__ unsigned char hitb[32][IDXSP][KNBR];    // 5 KB
    __shared__ unsigned char cnts[32][IDXSP];
    __shared__ unsigned short idxl[32][KNBR];
    __shared__ float  featw[4][KNBR][6];
    __shared__ double sred[4][27];
    const int b  = blockIdx.x >> 6;
    const int qg = blockIdx.x & 63;
    const float* xb = x + (size_t)b * NPTS * 3;
    for (int i = threadIdx.x; i < NPTS; i += 256)
        pts[i] = stage4(xb[i*3+0], xb[i*3+1], xb[i*3+2]);
    __syncthreads();
    // ---- phase A ----
    {
        const int qi = threadIdx.x >> 3;
        const int sp = threadIdx.x & 7;
        const int n  = qg * 32 + qi;
        const float4 qc = pts[n];
        const float4 q = make_float4(0.5f*qc.x, 0.5f*qc.y, 0.5f*qc.z, qc.w);
        const float th = thresh[(size_t)b * NPTS + n];
        int lc = 0;
        const int j0 = sp * IDXSZ;
        for (int j = j0; j < j0 + IDXSZ; ++j) {
            float d = dist_eval(q, pts[j]);
            if (d >= th) { if (lc < KNBR) hitb[qi][sp][lc] = (unsigned char)(j - j0); ++lc; }
        }
        cnts[qi][sp] = (unsigned char)(lc < KNBR ? lc : KNBR);
        __syncthreads();
        int base = 0;
        for (int s = 0; s < sp; ++s) base += cnts[qi][s];
        const int lim = cnts[qi][sp];
        for (int l = 0; l < lim; ++l) {
            int r = base + l;
            if (r < KNBR) idxl[qi][r] = (unsigned short)(j0 + (int)hitb[qi][sp][l]);
        }
    }
    __syncthreads();
    // ---- phase B ----
    const int wv = threadIdx.x >> 6, lane = threadIdx.x & 63;
    float cw[6];
#pragma unroll
    for (int c = 0; c < 6; ++c) cw[c] = conv_w[lane*6 + c];
    int pa_ = 0, pb_ = 0;
    if (lane >= 6 && lane < 27) {
        int t = lane - 6, a = 0;
        while (t >= 6 - a) { t -= 6 - a; ++a; }
        pa_ = a; pb_ = a + t;
    }
    double acc = 0.0;
    for (int i = 0; i < 8; ++i) {
        const int p = wv * 8 + i;
        const int nn = qg * 32 + p;
        const size_t bp = (size_t)b * NPTS + nn;
        const float4 Ci = pts[nn];
        const float xi0 = 0.5f*Ci.x, xi1 = 0.5f*Ci.y, xi2 = 0.5f*Ci.z;
        float f0=0,f1=0,f2=0,f3=0,f4=0,f5=0;
        if (lane < KNBR) {
            const float4 Cj = pts[idxl[p][lane]];
            f0 = 0.5f*(Cj.x - Ci.x);   // == fl(xj - xi) exactly
            f1 = 0.5f*(Cj.y - Ci.y);
            f2 = 0.5f*(Cj.z - Ci.z);
            f3 = xi0; f4 = xi1; f5 = xi2;
        }
        __syncthreads();
        if (lane < KNBR) {
            featw[wv][lane][0]=f0; featw[wv][lane][1]=f1; featw[wv][lane][2]=f2;
            featw[wv][lane][3]=f3; featw[wv][lane][4]=f4; featw[wv][lane][5]=f5;
        }
        __syncthreads();
        float vmax = -__builtin_inff(), vmin = __builtin_inff();
#pragma unroll
        for (int k = 0; k < KNBR; ++k) {
            float h = featw[wv][k][0] * cw[0];
            h = fmaf(featw[wv][k][1], cw[1], h);
            h = fmaf(featw[wv][k][2], cw[2], h);
            h = fmaf(featw[wv][k][3], cw[3], h);
            h = fmaf(featw[wv][k][4], cw[4], h);
            h = fmaf(featw[wv][k][5], cw[5], h);
            vmax = fmaxf(vmax, h); vmin = fminf(vmin, h);
        }
        maxh[bp*64 + lane] = vmax;
        minh[bp*64 + lane] = vmin;
        if (lane < 6) {
            double s = 0;
#pragma unroll
            for (int k = 0; k < KNBR; ++k) s += (double)featw[wv][k][lane];
            acc += s;
        } else if (lane < 27) {
            double s = 0;
#pragma unroll
            for (int k = 0; k < KNBR; ++k)
                s += (double)featw[wv][k][pa_] * (double)featw[wv][k][pb_];
            acc += s;
        }
    }
    if (lane < 27) sred[wv][lane] = acc;
    __syncthreads();
    if (threadIdx.x < 27) {
        double tot = sred[0][threadIdx.x] + sred[1][threadIdx.x]
                   + sred[2][threadIdx.x] + sred[3][threadIdx.x];
        atomicAdd(&S[threadIdx.x], tot);
    }
}

__global__ void stats0_kernel(const double* __restrict__ S, const float* __restrict__ conv_w,
        const float* __restrict__ g, const float* __restrict__ bb,
        float* __restrict__ scale, float* __restrict__ shift)
{
    const int o = threadIdx.x;
    double w[6];
#pragma unroll
    for (int c = 0; c < 6; ++c) w[c] = (double)conv_w[o*6 + c];
    double mean = 0.0;
#pragma unroll
    for (int c = 0; c < 6; ++c) mean += w[c] * S[c];
    mean /= CONV_M;
    double ey2 = 0.0;
    int t = 6;
#pragma unroll
    for (int a = 0; a < 6; ++a)
#pragma unroll
        for (int b2 = a; b2 < 6; ++b2) {
            double coef = (a == b2) ? 1.0 : 2.0;
            ey2 += coef * w[a] * w[b2] * S[t];
            ++t;
        }
    ey2 /= CONV_M;
    double var = ey2 - mean * mean;
    double sc = (double)g[o] / sqrt(var + BN_EPS);
    scale[o] = (float)sc;
    shift[o] = (float)((double)bb[o] - mean * sc);
}

__global__ void statsL_kernel(const double* __restrict__ sum, const double* __restrict__ sq,
        const float* __restrict__ g, const float* __restrict__ bt,
        float* __restrict__ scale, float* __restrict__ shift, int C)
{
    const int o = threadIdx.x;
    if (o >= C) return;
    double m = sum[o] / ROW_M;
    double v = sq[o] / ROW_M - m * m;
    double sc = (double)g[o] / sqrt(v + BN_EPS);
    scale[o] = (float)sc;
    shift[o] = (float)((double)bt[o] - m * sc);
}

// ---------------------------------------------------------------------------
// MLP GEMM: BM=64 rows/block, full N, BK=64. Swizzled transposed A tile,
// BN+lrelu fused into staging; column stats fused into epilogue.
// POOLOUT: no Y store; emit per-block per-channel max/min partials instead.
// ---------------------------------------------------------------------------
template<int K, int N, bool SEL, bool POOLOUT>
__global__ __launch_bounds__(256) void mlp_gemm(const float* __restrict__ A,
        const float* __restrict__ A2, const float* __restrict__ sc_,
        const float* __restrict__ sh_, const float* __restrict__ W,
        const float* __restrict__ bias, float* __restrict__ Y,
        double* __restrict__ sum, double* __restrict__ sq,
        float* __restrict__ pmax_g, float* __restrict__ pmin_g)
{
    constexpr int CPT = N / 16;                 // cols per thread (4 or 8)
    __shared__ float As[64 * 64];               // [k][row^swz], 16 KB
    __shared__ float Ws[64 * N];                // [k][n]
    const int tid = threadIdx.x;
    const int row0 = blockIdx.x * 64;
    const int ct = tid & 15, rt = tid >> 4;
    float acc[4][CPT];
#pragma unroll
    for (int rr = 0; rr < 4; ++rr)
#pragma unroll
        for (int cc = 0; cc < CPT; ++cc) acc[rr][cc] = bias[ct*CPT + cc];

    for (int kk = 0; kk < K/64; ++kk) {
        if (kk) __syncthreads();
#pragma unroll
        for (int i = 0; i < 4; ++i) {
            const int f   = i * 256 + tid;
            const int k4  = f & 15;
            const int row = f >> 4;
            const int kg  = kk*64 + k4*4;
            float4 m = *(const float4*)(A + (size_t)(row0+row)*K + kg);
            const float4 s4 = *(const float4*)(sc_ + kg);
            const float4 h4 = *(const float4*)(sh_ + kg);
            if (SEL) {
                float4 m2 = *(const float4*)(A2 + (size_t)(row0+row)*K + kg);
                m.x = s4.x >= 0.f ? m.x : m2.x;
                m.y = s4.y >= 0.f ? m.y : m2.y;
                m.z = s4.z >= 0.f ? m.z : m2.z;
                m.w = s4.w >= 0.f ? m.w : m2.w;
            }
            const int rsw = row ^ ((k4 & 7) << 2);
            As[(k4*4+0)*64 + rsw] = lrelu(fmaf(s4.x, m.x, h4.x));
            As[(k4*4+1)*64 + rsw] = lrelu(fmaf(s4.y, m.y, h4.y));
            As[(k4*4+2)*64 + rsw] = lrelu(fmaf(s4.z, m.z, h4.z));
            As[(k4*4+3)*64 + rsw] = lrelu(fmaf(s4.w, m.w, h4.w));
        }
#pragma unroll
        for (int i = 0; i < N/16; ++i) {
            const int f    = i * 256 + tid;
            const int col4 = f & (N/4 - 1);
            const int krow = f / (N/4);
            *(float4*)(&Ws[krow*N + col4*4]) =
                *(const float4*)(W + (size_t)(kk*64 + krow)*N + col4*4);
        }
        __syncthreads();
#pragma unroll 4
        for (int k = 0; k < 64; ++k) {
            const int sw = ((k >> 2) & 7) << 2;
            const float4 a0 = *(const float4*)(&As[k*64 + ((rt*4) ^ sw)]);
            float a_[4] = {a0.x, a0.y, a0.z, a0.w};
            float w_[CPT];
#pragma unroll
            for (int v = 0; v < CPT/4; ++v) {
                const float4 wv4 = *(const float4*)(&Ws[k*N + ct*CPT + v*4]);
                w_[v*4+0] = wv4.x; w_[v*4+1] = wv4.y; w_[v*4+2] = wv4.z; w_[v*4+3] = wv4.w;
            }
#pragma unroll
            for (int rr = 0; rr < 4; ++rr)
#pragma unroll
                for (int cc = 0; cc < CPT; ++cc)
                    acc[rr][cc] = fmaf(a_[rr], w_[cc], acc[rr][cc]);
        }
    }
    if (!POOLOUT) {
#pragma unroll
        for (int rr = 0; rr < 4; ++rr) {
            float* yo = Y + (size_t)(row0 + rt*4 + rr)*N + ct*CPT;
#pragma unroll
            for (int v = 0; v < CPT/4; ++v)
                *(float4*)(yo + v*4) = make_float4(acc[rr][v*4+0], acc[rr][v*4+1],
                                                   acc[rr][v*4+2], acc[rr][v*4+3]);
        }
    }
    __syncthreads();                  // LDS dead; reuse As/Ws
    float* cr  = As;                  // [2N] column sum/sq partials
    float* pmx = As + 512;            // [16][N] per-rt max
    float* pmn = Ws;                  // [16][N] per-rt min
    if (tid < 2*N) cr[tid] = 0.f;
    if (POOLOUT) {
#pragma unroll
        for (int cc = 0; cc < CPT; ++cc) {
            float vmax = fmaxf(fmaxf(acc[0][cc], acc[1][cc]), fmaxf(acc[2][cc], acc[3][cc]));
            float vmin = fminf(fminf(acc[0][cc], acc[1][cc]), fminf(acc[2][cc], acc[3][cc]));
            pmx[rt*N + ct*CPT + cc] = vmax;
            pmn[rt*N + ct*CPT + cc] = vmin;
        }
    }
    __syncthreads();
#pragma unroll
    for (int cc = 0; cc < CPT; ++cc) {
        float s = acc[0][cc] + acc[1][cc] + acc[2][cc] + acc[3][cc];
        float q = fmaf(acc[0][cc], acc[0][cc], 0.f);
        q = fmaf(acc[1][cc], acc[1][cc], q);
        q = fmaf(acc[2][cc], acc[2][cc], q);
        q = fmaf(acc[3][cc], acc[3][cc], q);
        atomicAdd(&cr[ct*CPT + cc], s);
        atomicAdd(&cr[N + ct*CPT + cc], q);
    }
    float rm = 0.f, rn = 0.f;
    if (POOLOUT && tid < N) {
        rm = pmx[tid]; rn = pmn[tid];
#pragma unroll
        for (int r = 1; r < 16; ++r) {
            rm = fmaxf(rm, pmx[r*N + tid]);
            rn = fminf(rn, pmn[r*N + tid]);
        }
    }
    __syncthreads();
    if (tid < N) {
        atomicAdd(&sum[tid], (double)cr[tid]);
        atomicAdd(&sq[tid],  (double)cr[N + tid]);
        if (POOLOUT) {
            pmax_g[(size_t)blockIdx.x * N + tid] = rm;
            pmin_g[(size_t)blockIdx.x * N + tid] = rn;
        }
    }
}

// ---------------------------------------------------------------------------
// Fused pool-finish + head. Block = batch b.
// pooled_ch = lrelu(BN(max_n y)) for sc>=0 else lrelu(BN(min_n y)) — bit-
// identical to per-n BN+lrelu then max (monotonicity).
// ---------------------------------------------------------------------------
__global__ __launch_bounds__(256) void headpool_kernel(const float* __restrict__ pmax_g,
        const float* __restrict__ pmin_g, const float* __restrict__ s3,
        const float* __restrict__ t3, const float* __restrict__ w4,
        const float* __restrict__ b4, const float* __restrict__ w5,
        const float* __restrict__ b5, float* __restrict__ out)
{
    __shared__ float xr[128];
    __shared__ float hh[512];
    const int b = blockIdx.x, t = threadIdx.x;
    if (t < 128) {
        const float* pm = pmax_g + (size_t)b * 32 * 128 + t;
        const float* pn = pmin_g + (size_t)b * 32 * 128 + t;
        float m = pm[0], n_ = pn[0];
#pragma unroll
        for (int r = 1; r < 32; ++r) {
            m  = fmaxf(m,  pm[r*128]);
            n_ = fminf(n_, pn[r*128]);
        }
        const float sc = s3[t], sh = t3[t];
        xr[t] = lrelu(sc >= 0.f ? fmaf(sc, m, sh) : fmaf(sc, n_, sh));
    }
    __syncthreads();
    float h0 = b4[t], h1 = b4[t + 256];
    for (int c = 0; c < 128; ++c) {
        float xc = xr[c];
        h0 = fmaf(xc, w4[c*512 + t],       h0);
        h1 = fmaf(xc, w4[c*512 + t + 256], h1);
    }
    hh[t]       = lrelu(h0);
    hh[t + 256] = lrelu(h1);
    __syncthreads();
    float acc = b5[t];
    for (int c = 0; c < 512; ++c)
        acc = fmaf(hh[c], w5[c*256 + t], acc);
    out[b*256 + t] = acc;
}

extern "C" void kernel_launch(void* const* d_in, const int* in_sizes, int n_in,
                              void* d_out, int out_size, void* d_ws, size_t ws_size,
                              hipStream_t stream)
{
    const float* x      = (const float*)d_in[0];
    const float* conv_w = (const float*)d_in[1];
    const float* conv_g = (const float*)d_in[2];
    const float* conv_b = (const float*)d_in[3];
    const float* w1  = (const float*)d_in[4];
    const float* b1  = (const float*)d_in[5];
    const float* g1  = (const float*)d_in[6];
    const float* bt1 = (const float*)d_in[7];
    const float* w2  = (const float*)d_in[8];
    const float* b2  = (const float*)d_in[9];
    const float* g2  = (const float*)d_in[10];
    const float* bt2 = (const float*)d_in[11];
    const float* w3  = (const float*)d_in[12];
    const float* b3  = (const float*)d_in[13];
    const float* g3  = (const float*)d_in[14];
    const float* bt3 = (const float*)d_in[15];
    const float* w4  = (const float*)d_in[16];
    const float* b4  = (const float*)d_in[17];
    const float* w5  = (const float*)d_in[18];
    const float* b5  = (const float*)d_in[19];

    char* p = (char*)d_ws;
    auto take = [&](size_t bytes) -> char* {
        char* r = p; p += (bytes + 255) & ~(size_t)255; return r;
    };
    double* S    = (double*)take(27 * 8);
    double* sum1 = (double*)take(64 * 8);
    double* sq1  = (double*)take(64 * 8);
    double* sum2 = (double*)take(128 * 8);
    double* sq2  = (double*)take(128 * 8);
    double* sum3 = (double*)take(128 * 8);
    double* sq3  = (double*)take(128 * 8);
    size_t zero_bytes = (size_t)(p - (char*)d_ws);
    float* scale0 = (float*)take(64 * 4);
    float* shift0 = (float*)take(64 * 4);
    float* scale1 = (float*)take(64 * 4);
    float* shift1 = (float*)take(64 * 4);
    float* scale2 = (float*)take(128 * 4);
    float* shift2 = (float*)take(128 * 4);
    float* scale3 = (float*)take(128 * 4);
    float* shift3 = (float*)take(128 * 4);
    float* pmaxg  = (float*)take((size_t)512 * 128 * 4);     // 256 KB
    float* pming  = (float*)take((size_t)512 * 128 * 4);     // 256 KB
    float* thresh = (float*)take((size_t)NROWS * 4);
    float* mm     = (float*)take((size_t)NROWS * 128 * 4);   // 16 MB
    float* maxh   = mm;
    float* minh   = mm + (size_t)NROWS * 64;
    float* y1     = (float*)take((size_t)NROWS * 64 * 4);    // 8 MB
    float* y2     = (float*)take((size_t)NROWS * 128 * 4);   // 16 MB
    float* P      = mm;   // alias: knn partials = 16*20*NROWS*4 = 41.94 MB
                          // spans mm+y1+y2 exactly; all dead before reuse

    hipMemsetAsync(d_ws, 0, zero_bytes, stream);
    knn_part  <<<dim3(NB * 8 * NCH), dim3(256), 0, stream>>>(x, P);
    knn_merge <<<dim3(NROWS / 256),  dim3(256), 0, stream>>>(P, thresh);
    idxfeat_kernel<<<dim3(NB * 64),  dim3(256), 0, stream>>>(x, thresh, conv_w, maxh, minh, S);
    stats0_kernel<<<dim3(1),         dim3(64),  0, stream>>>(S, conv_w, conv_g, conv_b, scale0, shift0);

    mlp_gemm<64,64,true,false>   <<<dim3(512), dim3(256), 0, stream>>>(maxh, minh, scale0, shift0, w1, b1, y1, sum1, sq1, nullptr, nullptr);
    statsL_kernel                <<<dim3(1),   dim3(64),  0, stream>>>(sum1, sq1, g1, bt1, scale1, shift1, 64);
    mlp_gemm<64,128,false,false> <<<dim3(512), dim3(256), 0, stream>>>(y1, y1, scale1, shift1, w2, b2, y2, sum2, sq2, nullptr, nullptr);
    statsL_kernel                <<<dim3(1),   dim3(128), 0, stream>>>(sum2, sq2, g2, bt2, scale2, shift2, 128);
    mlp_gemm<128,128,false,true> <<<dim3(512), dim3(256), 0, stream>>>(y2, y2, scale2, shift2, w3, b3, nullptr, sum3, sq3, pmaxg, pming);
    statsL_kernel                <<<dim3(1),   dim3(128), 0, stream>>>(sum3, sq3, g3, bt3, scale3, shift3, 128);

    headpool_kernel<<<dim3(NB),      dim3(256), 0, stream>>>(pmaxg, pming, scale3, shift3, w4, b4, w5, b5, (float*)d_out);
}

// Round 6
// 409.139 us; speedup vs baseline: 1.1393x; 1.1393x over previous
//
#include <hip/hip_runtime.h>
#include <math.h>

#define NB   16
#define NPTS 2048
#define KNBR 20
#define NCH  16           // knn chunks per query (pass A)
#define CHSZ (NPTS/NCH)   // 128
#define NROWS (NB*NPTS)          // 32768
#define CONV_M ((double)(NB)*(double)(NPTS)*(double)(KNBR))
#define ROW_M  ((double)NROWS)
#define BN_EPS 1e-5
#define LSLOPE 0.2f

__device__ __forceinline__ float lrelu(float v) { return v >= 0.f ? v : LSLOPE * v; }

// candidate staging: (2x, 2y, 2z, -|p|^2)   query: (x, y, z, -|q|^2)
__device__ __forceinline__ float4 stage4(float px, float py, float pz)
{
    return make_float4(px + px, py + py, pz + pz,
                       -fmaf(px, px, fmaf(py, py, pz * pz)));
}

// d = 2<q,c> - |q|^2 - |c|^2, identical op order in every knn kernel
__device__ __forceinline__ float dist_eval(float4 q, float4 c)
{
    float t = fmaf(c.x, q.x, fmaf(c.y, q.y, fmaf(c.z, q.z, q.w)));
    return t + c.w;
}

// pair-insert of sorted (t0 >= t1) into sorted-desc bestv[20]
__device__ __forceinline__ void pair_insert_sorted(float (&bestv)[KNBR], float t0, float t1)
{
#pragma unroll
    for (int j = 0; j < KNBR; ++j) {
        float bj = bestv[j];
        float nb  = fmaxf(bj, t0);
        float nt0 = __builtin_amdgcn_fmed3f(bj, t0, t1);
        float nt1 = fminf(bj, t1);
        bestv[j] = nb;
        t0 = nt0; t1 = nt1;
    }
}

// ---------------------------------------------------------------------------
// KNN pass A: thread = (query, chunk-pair). Two independent 20-entry cascades
// (chunks c0 and c0+8) interleaved for ILP; per-chunk insert order unchanged
// vs the 1-chunk version -> P bit-identical.
// ---------------------------------------------------------------------------
__global__ __launch_bounds__(256) void knn_part(const float* __restrict__ x,
                                                float* __restrict__ P)
{
    __shared__ float4 cpt[2*CHSZ];   // chunk c0 | chunk c0+8
    __shared__ float4 qpt[256];
    const int b  = blockIdx.x >> 6;
    const int qg = (blockIdx.x >> 3) & 7;
    const int c0 = blockIdx.x & 7;
    const float* xb = x + (size_t)b * NPTS * 3;
    {
        const int half = threadIdx.x >> 7;           // 0 or 1
        const int jloc = threadIdx.x & (CHSZ - 1);
        const int j = (c0 + half*8) * CHSZ + jloc;
        cpt[threadIdx.x] = stage4(xb[j*3+0], xb[j*3+1], xb[j*3+2]);
        const int n = qg * 256 + threadIdx.x;
        float px = xb[n*3+0], py = xb[n*3+1], pz = xb[n*3+2];
        qpt[threadIdx.x] = make_float4(px, py, pz,
                                       -fmaf(px, px, fmaf(py, py, pz * pz)));
    }
    __syncthreads();
    const float4 q = qpt[threadIdx.x];
    float bA[KNBR], bB[KNBR];
#pragma unroll
    for (int j = 0; j < KNBR; ++j) { bA[j] = -__builtin_inff(); bB[j] = -__builtin_inff(); }
    for (int m = 0; m < CHSZ; m += 2) {
        float dA0 = dist_eval(q, cpt[m]);
        float dA1 = dist_eval(q, cpt[m+1]);
        float dB0 = dist_eval(q, cpt[CHSZ + m]);
        float dB1 = dist_eval(q, cpt[CHSZ + m+1]);
        float tA0 = fmaxf(dA0, dA1), tA1 = fminf(dA0, dA1);
        float tB0 = fmaxf(dB0, dB1), tB1 = fminf(dB0, dB1);
#pragma unroll
        for (int j = 0; j < KNBR; ++j) {
            float aj = bA[j], bj = bB[j];
            float nbA = fmaxf(aj, tA0);
            float nbB = fmaxf(bj, tB0);
            float nA0 = __builtin_amdgcn_fmed3f(aj, tA0, tA1);
            float nB0 = __builtin_amdgcn_fmed3f(bj, tB0, tB1);
            float nA1 = fminf(aj, tA1);
            float nB1 = fminf(bj, tB1);
            bA[j] = nbA; bB[j] = nbB;
            tA0 = nA0; tA1 = nA1; tB0 = nB0; tB1 = nB1;
        }
    }
    const size_t bq = (size_t)b * NPTS + qg * 256 + threadIdx.x;
#pragma unroll
    for (int i = 0; i < KNBR; ++i) {
        P[(size_t)(c0 * KNBR + i) * NROWS + bq]       = bA[i];
        P[(size_t)((c0+8) * KNBR + i) * NROWS + bq]   = bB[i];
    }
}

// ---------------------------------------------------------------------------
// KNN pass B: merge 16 sorted top-20 lists -> exact 20th-largest.
// Per-chunk early break: lists sorted desc, so a failed pair proves the rest
// of the chunk is a no-op (med3 carry stationary) for every lane.
// ---------------------------------------------------------------------------
__global__ __launch_bounds__(256) void knn_merge(const float* __restrict__ P,
                                                 float* __restrict__ thresh)
{
    const size_t bq = (size_t)blockIdx.x * 256 + threadIdx.x;
    float bestv[KNBR];
#pragma unroll
    for (int j = 0; j < KNBR; ++j) bestv[j] = -__builtin_inff();
    for (int c = 0; c < NCH; ++c) {
        for (int i = 0; i < KNBR; i += 2) {
            float d0 = P[(size_t)(c * KNBR + i)     * NROWS + bq];  // d0 >= d1
            float d1 = P[(size_t)(c * KNBR + i + 1) * NROWS + bq];
            if (!__any(d0 > bestv[KNBR-1])) break;
            pair_insert_sorted(bestv, d0, d1);
        }
    }
    thresh[bq] = bestv[KNBR-1];
}

// ---------------------------------------------------------------------------
// Fused index recovery + edge-conv. Block = (b, 32 queries).
// Phase A: wave-per-8-queries, ballot/popcount hit compaction, stride-1
// conflict-free pts reads, ascending-m tie-exact selection.
// Phase B: wave-per-64-channels edge conv, gathers from LDS pts.
// ---------------------------------------------------------------------------
__global__ __launch_bounds__(256) void idxfeat_kernel(const float* __restrict__ x,
        const float* __restrict__ thresh, const float* __restrict__ conv_w,
        float* __restrict__ maxh, float* __restrict__ minh, double* __restrict__ S)
{
    __shared__ float4 pts[NPTS];                       // 32 KB (2x,2y,2z,-xx)
    __shared__ unsigned short idxl[32][KNBR];
    __shared__ float  featw[4][KNBR][6];
    __shared__ double sred[4][27];
    const int b  = blockIdx.x >> 6;
    const int qg = blockIdx.x & 63;
    const int wv = threadIdx.x >> 6, lane = threadIdx.x & 63;
    const float* xb = x + (size_t)b * NPTS * 3;
    for (int i = threadIdx.x; i < NPTS; i += 256)
        pts[i] = stage4(xb[i*3+0], xb[i*3+1], xb[i*3+2]);
    __syncthreads();
    // ---- phase A: wave wv recovers indices for queries wv*8 .. wv*8+7 ----
    const unsigned long long below = (1ull << lane) - 1ull;
    for (int qi = 0; qi < 8; ++qi) {
        const int p = wv * 8 + qi;
        const int n = qg * 32 + p;
        const float4 qc = pts[n];
        const float4 q = make_float4(0.5f*qc.x, 0.5f*qc.y, 0.5f*qc.z, qc.w);
        const float th = thresh[(size_t)b * NPTS + n];
        int cnt = 0;
        for (int it = 0; it < NPTS/64; ++it) {
            float d = dist_eval(q, pts[it*64 + lane]);
            const bool hit = (d >= th);
            unsigned long long mask = __ballot(hit);
            int pos = cnt + __popcll(mask & below);
            if (hit && pos < KNBR)
                idxl[p][pos] = (unsigned short)(it*64 + lane);
            cnt += __popcll(mask);
        }
    }
    __syncthreads();
    // ---- phase B ----
    float cw[6];
#pragma unroll
    for (int c = 0; c < 6; ++c) cw[c] = conv_w[lane*6 + c];
    int pa_ = 0, pb_ = 0;
    if (lane >= 6 && lane < 27) {
        int t = lane - 6, a = 0;
        while (t >= 6 - a) { t -= 6 - a; ++a; }
        pa_ = a; pb_ = a + t;
    }
    double acc = 0.0;
    for (int i = 0; i < 8; ++i) {
        const int p = wv * 8 + i;
        const int nn = qg * 32 + p;
        const size_t bp = (size_t)b * NPTS + nn;
        const float4 Ci = pts[nn];
        const float xi0 = 0.5f*Ci.x, xi1 = 0.5f*Ci.y, xi2 = 0.5f*Ci.z;
        float f0=0,f1=0,f2=0,f3=0,f4=0,f5=0;
        if (lane < KNBR) {
            const float4 Cj = pts[idxl[p][lane]];
            f0 = 0.5f*(Cj.x - Ci.x);   // == fl(xj - xi) exactly
            f1 = 0.5f*(Cj.y - Ci.y);
            f2 = 0.5f*(Cj.z - Ci.z);
            f3 = xi0; f4 = xi1; f5 = xi2;
        }
        __syncthreads();
        if (lane < KNBR) {
            featw[wv][lane][0]=f0; featw[wv][lane][1]=f1; featw[wv][lane][2]=f2;
            featw[wv][lane][3]=f3; featw[wv][lane][4]=f4; featw[wv][lane][5]=f5;
        }
        __syncthreads();
        float vmax = -__builtin_inff(), vmin = __builtin_inff();
#pragma unroll
        for (int k = 0; k < KNBR; ++k) {
            float h = featw[wv][k][0] * cw[0];
            h = fmaf(featw[wv][k][1], cw[1], h);
            h = fmaf(featw[wv][k][2], cw[2], h);
            h = fmaf(featw[wv][k][3], cw[3], h);
            h = fmaf(featw[wv][k][4], cw[4], h);
            h = fmaf(featw[wv][k][5], cw[5], h);
            vmax = fmaxf(vmax, h); vmin = fminf(vmin, h);
        }
        maxh[bp*64 + lane] = vmax;
        minh[bp*64 + lane] = vmin;
        if (lane < 6) {
            double s = 0;
#pragma unroll
            for (int k = 0; k < KNBR; ++k) s += (double)featw[wv][k][lane];
            acc += s;
        } else if (lane < 27) {
            double s = 0;
#pragma unroll
            for (int k = 0; k < KNBR; ++k)
                s += (double)featw[wv][k][pa_] * (double)featw[wv][k][pb_];
            acc += s;
        }
    }
    if (lane < 27) sred[wv][lane] = acc;
    __syncthreads();
    if (threadIdx.x < 27) {
        double tot = sred[0][threadIdx.x] + sred[1][threadIdx.x]
                   + sred[2][threadIdx.x] + sred[3][threadIdx.x];
        atomicAdd(&S[threadIdx.x], tot);
    }
}

__global__ void stats0_kernel(const double* __restrict__ S, const float* __restrict__ conv_w,
        const float* __restrict__ g, const float* __restrict__ bb,
        float* __restrict__ scale, float* __restrict__ shift)
{
    const int o = threadIdx.x;
    double w[6];
#pragma unroll
    for (int c = 0; c < 6; ++c) w[c] = (double)conv_w[o*6 + c];
    double mean = 0.0;
#pragma unroll
    for (int c = 0; c < 6; ++c) mean += w[c] * S[c];
    mean /= CONV_M;
    double ey2 = 0.0;
    int t = 6;
#pragma unroll
    for (int a = 0; a < 6; ++a)
#pragma unroll
        for (int b2 = a; b2 < 6; ++b2) {
            double coef = (a == b2) ? 1.0 : 2.0;
            ey2 += coef * w[a] * w[b2] * S[t];
            ++t;
        }
    ey2 /= CONV_M;
    double var = ey2 - mean * mean;
    double sc = (double)g[o] / sqrt(var + BN_EPS);
    scale[o] = (float)sc;
    shift[o] = (float)((double)bb[o] - mean * sc);
}

__global__ void statsL_kernel(const double* __restrict__ sum, const double* __restrict__ sq,
        const float* __restrict__ g, const float* __restrict__ bt,
        float* __restrict__ scale, float* __restrict__ shift, int C)
{
    const int o = threadIdx.x;
    if (o >= C) return;
    double m = sum[o] / ROW_M;
    double v = sq[o] / ROW_M - m * m;
    double sc = (double)g[o] / sqrt(v + BN_EPS);
    scale[o] = (float)sc;
    shift[o] = (float)((double)bt[o] - m * sc);
}

// ---------------------------------------------------------------------------
// MLP GEMM: BM=64 rows/block, full N, BK=64. Swizzled transposed A tile,
// BN+lrelu fused into staging; column stats fused into epilogue.
// POOLOUT: no Y store; emit per-block per-channel max/min partials instead.
// ---------------------------------------------------------------------------
template<int K, int N, bool SEL, bool POOLOUT>
__global__ __launch_bounds__(256) void mlp_gemm(const float* __restrict__ A,
        const float* __restrict__ A2, const float* __restrict__ sc_,
        const float* __restrict__ sh_, const float* __restrict__ W,
        const float* __restrict__ bias, float* __restrict__ Y,
        double* __restrict__ sum, double* __restrict__ sq,
        float* __restrict__ pmax_g, float* __restrict__ pmin_g)
{
    constexpr int CPT = N / 16;                 // cols per thread (4 or 8)
    __shared__ float As[64 * 64];               // [k][row^swz], 16 KB
    __shared__ float Ws[64 * N];                // [k][n]
    const int tid = threadIdx.x;
    const int row0 = blockIdx.x * 64;
    const int ct = tid & 15, rt = tid >> 4;
    float acc[4][CPT];
#pragma unroll
    for (int rr = 0; rr < 4; ++rr)
#pragma unroll
        for (int cc = 0; cc < CPT; ++cc) acc[rr][cc] = bias[ct*CPT + cc];

    for (int kk = 0; kk < K/64; ++kk) {
        if (kk) __syncthreads();
#pragma unroll
        for (int i = 0; i < 4; ++i) {
            const int f   = i * 256 + tid;
            const int k4  = f & 15;
            const int row = f >> 4;
            const int kg  = kk*64 + k4*4;
            float4 m = *(const float4*)(A + (size_t)(row0+row)*K + kg);
            const float4 s4 = *(const float4*)(sc_ + kg);
            const float4 h4 = *(const float4*)(sh_ + kg);
            if (SEL) {
                float4 m2 = *(const float4*)(A2 + (size_t)(row0+row)*K + kg);
                m.x = s4.x >= 0.f ? m.x : m2.x;
                m.y = s4.y >= 0.f ? m.y : m2.y;
                m.z = s4.z >= 0.f ? m.z : m2.z;
                m.w = s4.w >= 0.f ? m.w : m2.w;
            }
            const int rsw = row ^ ((k4 & 7) << 2);
            As[(k4*4+0)*64 + rsw] = lrelu(fmaf(s4.x, m.x, h4.x));
            As[(k4*4+1)*64 + rsw] = lrelu(fmaf(s4.y, m.y, h4.y));
            As[(k4*4+2)*64 + rsw] = lrelu(fmaf(s4.z, m.z, h4.z));
            As[(k4*4+3)*64 + rsw] = lrelu(fmaf(s4.w, m.w, h4.w));
        }
#pragma unroll
        for (int i = 0; i < N/16; ++i) {
            const int f    = i * 256 + tid;
            const int col4 = f & (N/4 - 1);
            const int krow = f / (N/4);
            *(float4*)(&Ws[krow*N + col4*4]) =
                *(const float4*)(W + (size_t)(kk*64 + krow)*N + col4*4);
        }
        __syncthreads();
#pragma unroll 4
        for (int k = 0; k < 64; ++k) {
            const int sw = ((k >> 2) & 7) << 2;
            const float4 a0 = *(const float4*)(&As[k*64 + ((rt*4) ^ sw)]);
            float a_[4] = {a0.x, a0.y, a0.z, a0.w};
            float w_[CPT];
#pragma unroll
            for (int v = 0; v < CPT/4; ++v) {
                const float4 wv4 = *(const float4*)(&Ws[k*N + ct*CPT + v*4]);
                w_[v*4+0] = wv4.x; w_[v*4+1] = wv4.y; w_[v*4+2] = wv4.z; w_[v*4+3] = wv4.w;
            }
#pragma unroll
            for (int rr = 0; rr < 4; ++rr)
#pragma unroll
                for (int cc = 0; cc < CPT; ++cc)
                    acc[rr][cc] = fmaf(a_[rr], w_[cc], acc[rr][cc]);
        }
    }
    if (!POOLOUT) {
#pragma unroll
        for (int rr = 0; rr < 4; ++rr) {
            float* yo = Y + (size_t)(row0 + rt*4 + rr)*N + ct*CPT;
#pragma unroll
            for (int v = 0; v < CPT/4; ++v)
                *(float4*)(yo + v*4) = make_float4(acc[rr][v*4+0], acc[rr][v*4+1],
                                                   acc[rr][v*4+2], acc[rr][v*4+3]);
        }
    }
    __syncthreads();                  // LDS dead; reuse As/Ws
    float* cr  = As;                  // [2N] column sum/sq partials
    float* pmx = As + 512;            // [16][N] per-rt max
    float* pmn = Ws;                  // [16][N] per-rt min
    if (tid < 2*N) cr[tid] = 0.f;
    if (POOLOUT) {
#pragma unroll
        for (int cc = 0; cc < CPT; ++cc) {
            float vmax = fmaxf(fmaxf(acc[0][cc], acc[1][cc]), fmaxf(acc[2][cc], acc[3][cc]));
            float vmin = fminf(fminf(acc[0][cc], acc[1][cc]), fminf(acc[2][cc], acc[3][cc]));
            pmx[rt*N + ct*CPT + cc] = vmax;
            pmn[rt*N + ct*CPT + cc] = vmin;
        }
    }
    __syncthreads();
#pragma unroll
    for (int cc = 0; cc < CPT; ++cc) {
        float s = acc[0][cc] + acc[1][cc] + acc[2][cc] + acc[3][cc];
        float q = fmaf(acc[0][cc], acc[0][cc], 0.f);
        q = fmaf(acc[1][cc], acc[1][cc], q);
        q = fmaf(acc[2][cc], acc[2][cc], q);
        q = fmaf(acc[3][cc], acc[3][cc], q);
        atomicAdd(&cr[ct*CPT + cc], s);
        atomicAdd(&cr[N + ct*CPT + cc], q);
    }
    float rm = 0.f, rn = 0.f;
    if (POOLOUT && tid < N) {
        rm = pmx[tid]; rn = pmn[tid];
#pragma unroll
        for (int r = 1; r < 16; ++r) {
            rm = fmaxf(rm, pmx[r*N + tid]);
            rn = fminf(rn, pmn[r*N + tid]);
        }
    }
    __syncthreads();
    if (tid < N) {
        atomicAdd(&sum[tid], (double)cr[tid]);
        atomicAdd(&sq[tid],  (double)cr[N + tid]);
        if (POOLOUT) {
            pmax_g[(size_t)blockIdx.x * N + tid] = rm;
            pmin_g[(size_t)blockIdx.x * N + tid] = rn;
        }
    }
}

// ---------------------------------------------------------------------------
// Fused pool-finish + head. Block = batch b.
// ---------------------------------------------------------------------------
__global__ __launch_bounds__(256) void headpool_kernel(const float* __restrict__ pmax_g,
        const float* __restrict__ pmin_g, const float* __restrict__ s3,
        const float* __restrict__ t3, const float* __restrict__ w4,
        const float* __restrict__ b4, const float* __restrict__ w5,
        const float* __restrict__ b5, float* __restrict__ out)
{
    __shared__ float xr[128];
    __shared__ float hh[512];
    const int b = blockIdx.x, t = threadIdx.x;
    if (t < 128) {
        const float* pm = pmax_g + (size_t)b * 32 * 128 + t;
        const float* pn = pmin_g + (size_t)b * 32 * 128 + t;
        float m = pm[0], n_ = pn[0];
#pragma unroll
        for (int r = 1; r < 32; ++r) {
            m  = fmaxf(m,  pm[r*128]);
            n_ = fminf(n_, pn[r*128]);
        }
        const float sc = s3[t], sh = t3[t];
        xr[t] = lrelu(sc >= 0.f ? fmaf(sc, m, sh) : fmaf(sc, n_, sh));
    }
    __syncthreads();
    float h0 = b4[t], h1 = b4[t + 256];
    for (int c = 0; c < 128; ++c) {
        float xc = xr[c];
        h0 = fmaf(xc, w4[c*512 + t],       h0);
        h1 = fmaf(xc, w4[c*512 + t + 256], h1);
    }
    hh[t]       = lrelu(h0);
    hh[t + 256] = lrelu(h1);
    __syncthreads();
    float acc = b5[t];
    for (int c = 0; c < 512; ++c)
        acc = fmaf(hh[c], w5[c*256 + t], acc);
    out[b*256 + t] = acc;
}

extern "C" void kernel_launch(void* const* d_in, const int* in_sizes, int n_in,
                              void* d_out, int out_size, void* d_ws, size_t ws_size,
                              hipStream_t stream)
{
    const float* x      = (const float*)d_in[0];
    const float* conv_w = (const float*)d_in[1];
    const float* conv_g = (const float*)d_in[2];
    const float* conv_b = (const float*)d_in[3];
    const float* w1  = (const float*)d_in[4];
    const float* b1  = (const float*)d_in[5];
    const float* g1  = (const float*)d_in[6];
    const float* bt1 = (const float*)d_in[7];
    const float* w2  = (const float*)d_in[8];
    const float* b2  = (const float*)d_in[9];
    const float* g2  = (const float*)d_in[10];
    const float* bt2 = (const float*)d_in[11];
    const float* w3  = (const float*)d_in[12];
    const float* b3  = (const float*)d_in[13];
    const float* g3  = (const float*)d_in[14];
    const float* bt3 = (const float*)d_in[15];
    const float* w4  = (const float*)d_in[16];
    const float* b4  = (const float*)d_in[17];
    const float* w5  = (const float*)d_in[18];
    const float* b5  = (const float*)d_in[19];

    char* p = (char*)d_ws;
    auto take = [&](size_t bytes) -> char* {
        char* r = p; p += (bytes + 255) & ~(size_t)255; return r;
    };
    double* S    = (double*)take(27 * 8);
    double* sum1 = (double*)take(64 * 8);
    double* sq1  = (double*)take(64 * 8);
    double* sum2 = (double*)take(128 * 8);
    double* sq2  = (double*)take(128 * 8);
    double* sum3 = (double*)take(128 * 8);
    double* sq3  = (double*)take(128 * 8);
    size_t zero_bytes = (size_t)(p - (char*)d_ws);
    float* scale0 = (float*)take(64 * 4);
    float* shift0 = (float*)take(64 * 4);
    float* scale1 = (float*)take(64 * 4);
    float* shift1 = (float*)take(64 * 4);
    float* scale2 = (float*)take(128 * 4);
    float* shift2 = (float*)take(128 * 4);
    float* scale3 = (float*)take(128 * 4);
    float* shift3 = (float*)take(128 * 4);
    float* pmaxg  = (float*)take((size_t)512 * 128 * 4);     // 256 KB
    float* pming  = (float*)take((size_t)512 * 128 * 4);     // 256 KB
    float* thresh = (float*)take((size_t)NROWS * 4);
    float* mm     = (float*)take((size_t)NROWS * 128 * 4);   // 16 MB
    float* maxh   = mm;
    float* minh   = mm + (size_t)NROWS * 64;
    float* y1     = (float*)take((size_t)NROWS * 64 * 4);    // 8 MB
    float* y2     = (float*)take((size_t)NROWS * 128 * 4);   // 16 MB
    float* P      = mm;   // alias: knn partials = 16*20*NROWS*4 = 41.94 MB
                          // spans mm+y1+y2 exactly; all dead before reuse

    hipMemsetAsync(d_ws, 0, zero_bytes, stream);
    knn_part  <<<dim3(NB * 8 * 8),   dim3(256), 0, stream>>>(x, P);
    knn_merge <<<dim3(NROWS / 256),  dim3(256), 0, stream>>>(P, thresh);
    idxfeat_kernel<<<dim3(NB * 64),  dim3(256), 0, stream>>>(x, thresh, conv_w, maxh, minh, S);
    stats0_kernel<<<dim3(1),         dim3(64),  0, stream>>>(S, conv_w, conv_g, conv_b, scale0, shift0);

    mlp_gemm<64,64,true,false>   <<<dim3(512), dim3(256), 0, stream>>>(maxh, minh, scale0, shift0, w1, b1, y1, sum1, sq1, nullptr, nullptr);
    statsL_kernel                <<<dim3(1),   dim3(64),  0, stream>>>(sum1, sq1, g1, bt1, scale1, shift1, 64);
    mlp_gemm<64,128,false,false> <<<dim3(512), dim3(256), 0, stream>>>(y1, y1, scale1, shift1, w2, b2, y2, sum2, sq2, nullptr, nullptr);
    statsL_kernel                <<<dim3(1),   dim3(128), 0, stream>>>(sum2, sq2, g2, bt2, scale2, shift2, 128);
    mlp_gemm<128,128,false,true> <<<dim3(512), dim3(256), 0, stream>>>(y2, y2, scale2, shift2, w3, b3, nullptr, sum3, sq3, pmaxg, pming);
    statsL_kernel                <<<dim3(1),   dim3(128), 0, stream>>>(sum3, sq3, g3, bt3, scale3, shift3, 128);

    headpool_kernel<<<dim3(NB),      dim3(256), 0, stream>>>(pmaxg, pming, scale3, shift3, w4, b4, w5, b5, (float*)d_out);
}

// Round 7
// 391.466 us; speedup vs baseline: 1.1907x; 1.0451x over previous
//
#include <hip/hip_runtime.h>
#include <math.h>

#define NB   16
#define NPTS 2048
#define KNBR 20
#define NROWS (NB*NPTS)          // 32768
#define CONV_M ((double)(NB)*(double)(NPTS)*(double)(KNBR))
#define ROW_M  ((double)NROWS)
#define BN_EPS 1e-5
#define LSLOPE 0.2f

__device__ __forceinline__ float lrelu(float v) { return v >= 0.f ? v : LSLOPE * v; }

// candidate staging: (2x, 2y, 2z, -|p|^2)   query: (x, y, z, -|q|^2)
__device__ __forceinline__ float4 stage4(float px, float py, float pz)
{
    return make_float4(px + px, py + py, pz + pz,
                       -fmaf(px, px, fmaf(py, py, pz * pz)));
}

// d = 2<q,c> - |q|^2 - |c|^2  (same op order as all prior rounds)
__device__ __forceinline__ float dist_eval(float4 q, float4 c)
{
    float t = fmaf(c.x, q.x, fmaf(c.y, q.y, fmaf(c.z, q.z, q.w)));
    return t + c.w;
}

// ---------------------------------------------------------------------------
// Fused KNN-select + index recovery + edge-conv. Block = (b, 32 queries).
// Per wave x 8 queries (serial):
//   1) cache 2048 distances as order-mapped uints (32/lane)
//   2) bisect on uint space for the EXACT rank-20 value u* (count>=20
//      invariant; early-exit masked-min when count==20)
//   3) ballot/prefix index recovery (u >= u*), ascending order, tie-exact
// Then wave-per-64-channels edge conv from LDS pts.
// ---------------------------------------------------------------------------
__global__ __launch_bounds__(256) void knn_feat_kernel(const float* __restrict__ x,
        const float* __restrict__ conv_w,
        float* __restrict__ maxh, float* __restrict__ minh, double* __restrict__ S)
{
    __shared__ float4 pts[NPTS];                       // 32 KB (2x,2y,2z,-xx)
    __shared__ unsigned short idxl[32][KNBR];
    __shared__ float  featw[4][KNBR][6];
    __shared__ double sred[4][27];
    const int b  = blockIdx.x >> 6;
    const int qg = blockIdx.x & 63;
    const int wv = threadIdx.x >> 6, lane = threadIdx.x & 63;
    const float* xb = x + (size_t)b * NPTS * 3;
    for (int i = threadIdx.x; i < NPTS; i += 256)
        pts[i] = stage4(xb[i*3+0], xb[i*3+1], xb[i*3+2]);
    __syncthreads();

    const unsigned long long below = (1ull << lane) - 1ull;
    for (int qi = 0; qi < 8; ++qi) {
        const int p = wv * 8 + qi;
        const int n = qg * 32 + p;
        const float4 qc = pts[n];
        const float4 q = make_float4(0.5f*qc.x, 0.5f*qc.y, 0.5f*qc.z, qc.w);
        // 1) distance cache, order-preserving map f32 -> u32
        unsigned u[32];
#pragma unroll
        for (int it = 0; it < 32; ++it) {
            float d = dist_eval(q, pts[it*64 + lane]);
            unsigned bits = __float_as_uint(d);
            u[it] = bits ^ (unsigned)(((int)bits >> 31) | (int)0x80000000);
        }
        // 2) bisection select: largest u* with count(u >= u*) >= 20
        unsigned lo = 0u, hi = 0xFFFFFFFFu;   // count(>=lo)>=20 ; count(>=hi)<20
        for (int step = 0; step < 32; ++step) {
            const unsigned mid = lo + ((hi - lo) >> 1);
            int cnt = 0;
#pragma unroll
            for (int it = 0; it < 32; ++it)
                cnt += __popcll(__ballot(u[it] >= mid));
            if (cnt == KNBR) {                 // exact: u* = min{u : u >= mid}
                unsigned mn = 0xFFFFFFFFu;
#pragma unroll
                for (int it = 0; it < 32; ++it)
                    mn = (u[it] >= mid && u[it] < mn) ? u[it] : mn;
#pragma unroll
                for (int o = 32; o >= 1; o >>= 1) {
                    unsigned other = (unsigned)__shfl_xor((int)mn, o);
                    mn = other < mn ? other : mn;
                }
                lo = mn;
                break;
            }
            if (cnt > KNBR) lo = mid; else hi = mid;
        }
        const unsigned ustar = lo;
        // 3) index recovery (ascending it, ascending lane = ascending m)
        int cnt2 = 0;
#pragma unroll
        for (int it = 0; it < 32; ++it) {
            const bool hit = (u[it] >= ustar);
            unsigned long long mask = __ballot(hit);
            int pos = cnt2 + __popcll(mask & below);
            if (hit && pos < KNBR)
                idxl[p][pos] = (unsigned short)(it*64 + lane);
            cnt2 += __popcll(mask);
        }
    }
    __syncthreads();
    // ---- edge conv ----
    float cw[6];
#pragma unroll
    for (int c = 0; c < 6; ++c) cw[c] = conv_w[lane*6 + c];
    int pa_ = 0, pb_ = 0;
    if (lane >= 6 && lane < 27) {
        int t = lane - 6, a = 0;
        while (t >= 6 - a) { t -= 6 - a; ++a; }
        pa_ = a; pb_ = a + t;
    }
    double acc = 0.0;
    for (int i = 0; i < 8; ++i) {
        const int p = wv * 8 + i;
        const int nn = qg * 32 + p;
        const size_t bp = (size_t)b * NPTS + nn;
        const float4 Ci = pts[nn];
        const float xi0 = 0.5f*Ci.x, xi1 = 0.5f*Ci.y, xi2 = 0.5f*Ci.z;
        float f0=0,f1=0,f2=0,f3=0,f4=0,f5=0;
        if (lane < KNBR) {
            const float4 Cj = pts[idxl[p][lane]];
            f0 = 0.5f*(Cj.x - Ci.x);   // == fl(xj - xi) exactly
            f1 = 0.5f*(Cj.y - Ci.y);
            f2 = 0.5f*(Cj.z - Ci.z);
            f3 = xi0; f4 = xi1; f5 = xi2;
        }
        __syncthreads();
        if (lane < KNBR) {
            featw[wv][lane][0]=f0; featw[wv][lane][1]=f1; featw[wv][lane][2]=f2;
            featw[wv][lane][3]=f3; featw[wv][lane][4]=f4; featw[wv][lane][5]=f5;
        }
        __syncthreads();
        float vmax = -__builtin_inff(), vmin = __builtin_inff();
#pragma unroll
        for (int k = 0; k < KNBR; ++k) {
            float h = featw[wv][k][0] * cw[0];
            h = fmaf(featw[wv][k][1], cw[1], h);
            h = fmaf(featw[wv][k][2], cw[2], h);
            h = fmaf(featw[wv][k][3], cw[3], h);
            h = fmaf(featw[wv][k][4], cw[4], h);
            h = fmaf(featw[wv][k][5], cw[5], h);
            vmax = fmaxf(vmax, h); vmin = fminf(vmin, h);
        }
        maxh[bp*64 + lane] = vmax;
        minh[bp*64 + lane] = vmin;
        if (lane < 6) {
            double s = 0;
#pragma unroll
            for (int k = 0; k < KNBR; ++k) s += (double)featw[wv][k][lane];
            acc += s;
        } else if (lane < 27) {
            double s = 0;
#pragma unroll
            for (int k = 0; k < KNBR; ++k)
                s += (double)featw[wv][k][pa_] * (double)featw[wv][k][pb_];
            acc += s;
        }
    }
    if (lane < 27) sred[wv][lane] = acc;
    __syncthreads();
    if (threadIdx.x < 27) {
        double tot = sred[0][threadIdx.x] + sred[1][threadIdx.x]
                   + sred[2][threadIdx.x] + sred[3][threadIdx.x];
        atomicAdd(&S[threadIdx.x], tot);
    }
}

// ---------------------------------------------------------------------------
// MLP GEMM with in-kernel BN scale/shift derivation (identical double math
// per block -> identical floats; replicates old stats kernels bit-exactly).
// ---------------------------------------------------------------------------
template<int K, int N, bool SEL, bool POOLOUT, bool STATS0>
__global__ __launch_bounds__(256) void mlp_gemm(const float* __restrict__ A,
        const float* __restrict__ A2,
        const double* __restrict__ st_a, const double* __restrict__ st_b,
        const float* __restrict__ st_g, const float* __restrict__ st_bt,
        const float* __restrict__ cwm,
        const float* __restrict__ W, const float* __restrict__ bias,
        float* __restrict__ Y, double* __restrict__ sum, double* __restrict__ sq,
        float* __restrict__ pmax_g, float* __restrict__ pmin_g)
{
    constexpr int CPT = N / 16;                 // cols per thread (4 or 8)
    __shared__ float As[64 * 64];               // [k][row^swz], 16 KB
    __shared__ float Ws[64 * N];                // [k][n]
    __shared__ __align__(16) float s_scale[K], s_shift[K];
    const int tid = threadIdx.x;
    // ---- BN params for the INPUT, derived in-block (deterministic) ----
    if (tid < K) {
        const int o = tid;
        if (STATS0) {
            double w[6];
#pragma unroll
            for (int c = 0; c < 6; ++c) w[c] = (double)cwm[o*6 + c];
            double mean = 0.0;
#pragma unroll
            for (int c = 0; c < 6; ++c) mean += w[c] * st_a[c];
            mean /= CONV_M;
            double ey2 = 0.0;
            int t = 6;
#pragma unroll
            for (int a = 0; a < 6; ++a)
#pragma unroll
                for (int b2 = a; b2 < 6; ++b2) {
                    double coef = (a == b2) ? 1.0 : 2.0;
                    ey2 += coef * w[a] * w[b2] * st_a[t];
                    ++t;
                }
            ey2 /= CONV_M;
            double var = ey2 - mean * mean;
            double sc = (double)st_g[o] / sqrt(var + BN_EPS);
            s_scale[o] = (float)sc;
            s_shift[o] = (float)((double)st_bt[o] - mean * sc);
        } else {
            double m = st_a[o] / ROW_M;
            double v = st_b[o] / ROW_M - m * m;
            double sc = (double)st_g[o] / sqrt(v + BN_EPS);
            s_scale[o] = (float)sc;
            s_shift[o] = (float)((double)st_bt[o] - m * sc);
        }
    }
    const int row0 = blockIdx.x * 64;
    const int ct = tid & 15, rt = tid >> 4;
    float acc[4][CPT];
#pragma unroll
    for (int rr = 0; rr < 4; ++rr)
#pragma unroll
        for (int cc = 0; cc < CPT; ++cc) acc[rr][cc] = bias[ct*CPT + cc];
    __syncthreads();

    for (int kk = 0; kk < K/64; ++kk) {
        if (kk) __syncthreads();
#pragma unroll
        for (int i = 0; i < 4; ++i) {
            const int f   = i * 256 + tid;
            const int k4  = f & 15;
            const int row = f >> 4;
            const int kg  = kk*64 + k4*4;
            float4 m = *(const float4*)(A + (size_t)(row0+row)*K + kg);
            const float4 s4 = *(const float4*)(&s_scale[kg]);
            const float4 h4 = *(const float4*)(&s_shift[kg]);
            if (SEL) {
                float4 m2 = *(const float4*)(A2 + (size_t)(row0+row)*K + kg);
                m.x = s4.x >= 0.f ? m.x : m2.x;
                m.y = s4.y >= 0.f ? m.y : m2.y;
                m.z = s4.z >= 0.f ? m.z : m2.z;
                m.w = s4.w >= 0.f ? m.w : m2.w;
            }
            const int rsw = row ^ ((k4 & 7) << 2);
            As[(k4*4+0)*64 + rsw] = lrelu(fmaf(s4.x, m.x, h4.x));
            As[(k4*4+1)*64 + rsw] = lrelu(fmaf(s4.y, m.y, h4.y));
            As[(k4*4+2)*64 + rsw] = lrelu(fmaf(s4.z, m.z, h4.z));
            As[(k4*4+3)*64 + rsw] = lrelu(fmaf(s4.w, m.w, h4.w));
        }
#pragma unroll
        for (int i = 0; i < N/16; ++i) {
            const int f    = i * 256 + tid;
            const int col4 = f & (N/4 - 1);
            const int krow = f / (N/4);
            *(float4*)(&Ws[krow*N + col4*4]) =
                *(const float4*)(W + (size_t)(kk*64 + krow)*N + col4*4);
        }
        __syncthreads();
#pragma unroll 4
        for (int k = 0; k < 64; ++k) {
            const int sw = ((k >> 2) & 7) << 2;
            const float4 a0 = *(const float4*)(&As[k*64 + ((rt*4) ^ sw)]);
            float a_[4] = {a0.x, a0.y, a0.z, a0.w};
            float w_[CPT];
#pragma unroll
            for (int v = 0; v < CPT/4; ++v) {
                const float4 wv4 = *(const float4*)(&Ws[k*N + ct*CPT + v*4]);
                w_[v*4+0] = wv4.x; w_[v*4+1] = wv4.y; w_[v*4+2] = wv4.z; w_[v*4+3] = wv4.w;
            }
#pragma unroll
            for (int rr = 0; rr < 4; ++rr)
#pragma unroll
                for (int cc = 0; cc < CPT; ++cc)
                    acc[rr][cc] = fmaf(a_[rr], w_[cc], acc[rr][cc]);
        }
    }
    if (!POOLOUT) {
#pragma unroll
        for (int rr = 0; rr < 4; ++rr) {
            float* yo = Y + (size_t)(row0 + rt*4 + rr)*N + ct*CPT;
#pragma unroll
            for (int v = 0; v < CPT/4; ++v)
                *(float4*)(yo + v*4) = make_float4(acc[rr][v*4+0], acc[rr][v*4+1],
                                                   acc[rr][v*4+2], acc[rr][v*4+3]);
        }
    }
    __syncthreads();                  // LDS dead; reuse As/Ws
    float* cr  = As;                  // [2N] column sum/sq partials
    float* pmx = As + 512;            // [16][N] per-rt max
    float* pmn = Ws;                  // [16][N] per-rt min
    if (tid < 2*N) cr[tid] = 0.f;
    if (POOLOUT) {
#pragma unroll
        for (int cc = 0; cc < CPT; ++cc) {
            float vmax = fmaxf(fmaxf(acc[0][cc], acc[1][cc]), fmaxf(acc[2][cc], acc[3][cc]));
            float vmin = fminf(fminf(acc[0][cc], acc[1][cc]), fminf(acc[2][cc], acc[3][cc]));
            pmx[rt*N + ct*CPT + cc] = vmax;
            pmn[rt*N + ct*CPT + cc] = vmin;
        }
    }
    __syncthreads();
#pragma unroll
    for (int cc = 0; cc < CPT; ++cc) {
        float s = acc[0][cc] + acc[1][cc] + acc[2][cc] + acc[3][cc];
        float q = fmaf(acc[0][cc], acc[0][cc], 0.f);
        q = fmaf(acc[1][cc], acc[1][cc], q);
        q = fmaf(acc[2][cc], acc[2][cc], q);
        q = fmaf(acc[3][cc], acc[3][cc], q);
        atomicAdd(&cr[ct*CPT + cc], s);
        atomicAdd(&cr[N + ct*CPT + cc], q);
    }
    float rm = 0.f, rn = 0.f;
    if (POOLOUT && tid < N) {
        rm = pmx[tid]; rn = pmn[tid];
#pragma unroll
        for (int r = 1; r < 16; ++r) {
            rm = fmaxf(rm, pmx[r*N + tid]);
            rn = fminf(rn, pmn[r*N + tid]);
        }
    }
    __syncthreads();
    if (tid < N) {
        atomicAdd(&sum[tid], (double)cr[tid]);
        atomicAdd(&sq[tid],  (double)cr[N + tid]);
        if (POOLOUT) {
            pmax_g[(size_t)blockIdx.x * N + tid] = rm;
            pmin_g[(size_t)blockIdx.x * N + tid] = rn;
        }
    }
}

// ---------------------------------------------------------------------------
// Fused BN3-derive + pool-finish + head. Block = batch b.
// ---------------------------------------------------------------------------
__global__ __launch_bounds__(256) void headpool_kernel(const float* __restrict__ pmax_g,
        const float* __restrict__ pmin_g,
        const double* __restrict__ sum3, const double* __restrict__ sq3,
        const float* __restrict__ g3, const float* __restrict__ bt3,
        const float* __restrict__ w4, const float* __restrict__ b4,
        const float* __restrict__ w5, const float* __restrict__ b5,
        float* __restrict__ out)
{
    __shared__ float xr[128];
    __shared__ float hh[512];
    const int b = blockIdx.x, t = threadIdx.x;
    if (t < 128) {
        double m_ = sum3[t] / ROW_M;
        double v_ = sq3[t] / ROW_M - m_ * m_;
        double scd = (double)g3[t] / sqrt(v_ + BN_EPS);
        const float sc = (float)scd;
        const float sh = (float)((double)bt3[t] - m_ * scd);
        const float* pm = pmax_g + (size_t)b * 32 * 128 + t;
        const float* pn = pmin_g + (size_t)b * 32 * 128 + t;
        float m = pm[0], n_ = pn[0];
#pragma unroll
        for (int r = 1; r < 32; ++r) {
            m  = fmaxf(m,  pm[r*128]);
            n_ = fminf(n_, pn[r*128]);
        }
        xr[t] = lrelu(sc >= 0.f ? fmaf(sc, m, sh) : fmaf(sc, n_, sh));
    }
    __syncthreads();
    float h0 = b4[t], h1 = b4[t + 256];
    for (int c = 0; c < 128; ++c) {
        float xc = xr[c];
        h0 = fmaf(xc, w4[c*512 + t],       h0);
        h1 = fmaf(xc, w4[c*512 + t + 256], h1);
    }
    hh[t]       = lrelu(h0);
    hh[t + 256] = lrelu(h1);
    __syncthreads();
    float acc = b5[t];
    for (int c = 0; c < 512; ++c)
        acc = fmaf(hh[c], w5[c*256 + t], acc);
    out[b*256 + t] = acc;
}

extern "C" void kernel_launch(void* const* d_in, const int* in_sizes, int n_in,
                              void* d_out, int out_size, void* d_ws, size_t ws_size,
                              hipStream_t stream)
{
    const float* x      = (const float*)d_in[0];
    const float* conv_w = (const float*)d_in[1];
    const float* conv_g = (const float*)d_in[2];
    const float* conv_b = (const float*)d_in[3];
    const float* w1  = (const float*)d_in[4];
    const float* b1  = (const float*)d_in[5];
    const float* g1  = (const float*)d_in[6];
    const float* bt1 = (const float*)d_in[7];
    const float* w2  = (const float*)d_in[8];
    const float* b2  = (const float*)d_in[9];
    const float* g2  = (const float*)d_in[10];
    const float* bt2 = (const float*)d_in[11];
    const float* w3  = (const float*)d_in[12];
    const float* b3  = (const float*)d_in[13];
    const float* g3  = (const float*)d_in[14];
    const float* bt3 = (const float*)d_in[15];
    const float* w4  = (const float*)d_in[16];
    const float* b4  = (const float*)d_in[17];
    const float* w5  = (const float*)d_in[18];
    const float* b5  = (const float*)d_in[19];

    char* p = (char*)d_ws;
    auto take = [&](size_t bytes) -> char* {
        char* r = p; p += (bytes + 255) & ~(size_t)255; return r;
    };
    double* S    = (double*)take(27 * 8);
    double* sum1 = (double*)take(64 * 8);
    double* sq1  = (double*)take(64 * 8);
    double* sum2 = (double*)take(128 * 8);
    double* sq2  = (double*)take(128 * 8);
    double* sum3 = (double*)take(128 * 8);
    double* sq3  = (double*)take(128 * 8);
    size_t zero_bytes = (size_t)(p - (char*)d_ws);
    float* pmaxg  = (float*)take((size_t)512 * 128 * 4);     // 256 KB
    float* pming  = (float*)take((size_t)512 * 128 * 4);     // 256 KB
    float* mm     = (float*)take((size_t)NROWS * 128 * 4);   // 16 MB
    float* maxh   = mm;
    float* minh   = mm + (size_t)NROWS * 64;
    float* y1     = (float*)take((size_t)NROWS * 64 * 4);    // 8 MB
    float* y2     = (float*)take((size_t)NROWS * 128 * 4);   // 16 MB

    hipMemsetAsync(d_ws, 0, zero_bytes, stream);
    knn_feat_kernel<<<dim3(NB * 64), dim3(256), 0, stream>>>(x, conv_w, maxh, minh, S);

    mlp_gemm<64,64,true,false,true>    <<<dim3(512), dim3(256), 0, stream>>>(
        maxh, minh, S, nullptr, conv_g, conv_b, conv_w, w1, b1, y1, sum1, sq1, nullptr, nullptr);
    mlp_gemm<64,128,false,false,false> <<<dim3(512), dim3(256), 0, stream>>>(
        y1, y1, sum1, sq1, g1, bt1, nullptr, w2, b2, y2, sum2, sq2, nullptr, nullptr);
    mlp_gemm<128,128,false,true,false> <<<dim3(512), dim3(256), 0, stream>>>(
        y2, y2, sum2, sq2, g2, bt2, nullptr, w3, b3, nullptr, sum3, sq3, pmaxg, pming);

    headpool_kernel<<<dim3(NB), dim3(256), 0, stream>>>(
        pmaxg, pming, sum3, sq3, g3, bt3, w4, b4, w5, b5, (float*)d_out);
}

// Round 8
// 342.794 us; speedup vs baseline: 1.3598x; 1.1420x over previous
//
#include <hip/hip_runtime.h>
#include <math.h>

#define NB   16
#define NPTS 2048
#define KNBR 20
#define NROWS (NB*NPTS)          // 32768
#define CONV_M ((double)(NB)*(double)(NPTS)*(double)(KNBR))
#define ROW_M  ((double)NROWS)
#define BN_EPS 1e-5
#define LSLOPE 0.2f

__device__ __forceinline__ float lrelu(float v) { return v >= 0.f ? v : LSLOPE * v; }

// candidate staging: (2x, 2y, 2z, -|p|^2)   query: (x, y, z, -|q|^2)
__device__ __forceinline__ float4 stage4(float px, float py, float pz)
{
    return make_float4(px + px, py + py, pz + pz,
                       -fmaf(px, px, fmaf(py, py, pz * pz)));
}

// d = 2<q,c> - |q|^2 - |c|^2  (same op order as all prior rounds)
__device__ __forceinline__ float dist_eval(float4 q, float4 c)
{
    float t = fmaf(c.x, q.x, fmaf(c.y, q.y, fmaf(c.z, q.z, q.w)));
    return t + c.w;
}

// pair-insert of sorted (t0 >= t1) into sorted-desc bestv[20]
__device__ __forceinline__ void pair_insert_sorted(float (&bestv)[KNBR], float t0, float t1)
{
#pragma unroll
    for (int j = 0; j < KNBR; ++j) {
        float bj = bestv[j];
        float nb  = fmaxf(bj, t0);
        float nt0 = __builtin_amdgcn_fmed3f(bj, t0, t1);
        float nt1 = fminf(bj, t1);
        bestv[j] = nb;
        t0 = nt0; t1 = nt1;
    }
}

// ---------------------------------------------------------------------------
// Fused KNN (cascade+ring select, register tree-merge) + index recovery +
// edge-conv. Block = (b, 32 queries), 256 threads.
// Phase 0: thread = (query qi, chunk c of 8x256). Dense cascade on 64 rotated
//   candidates -> cross-chunk floor L (shfl) -> ring-buffered scan of the
//   remaining 192 (insert only if d > running-20th; wave-flush when any ring
//   ~full). Exact by padded-set semantics (floor L <= d20; drops are <=
//   running 20th; set-order independence of top-20).
// Merge: shfl_xor tree (1,2,4) with early-break pair_inserts -> thresh.
// Recovery: ballot/prefix, ascending order, tie-exact. Conv: unchanged.
// ---------------------------------------------------------------------------
__global__ __launch_bounds__(256) void knn_feat_kernel(const float* __restrict__ x,
        const float* __restrict__ conv_w,
        float* __restrict__ maxh, float* __restrict__ minh, double* __restrict__ S)
{
    __shared__ float4 pts[NPTS];                       // 32 KB (2x,2y,2z,-xx)
    __shared__ unsigned short idxl[32][KNBR];
    __shared__ float  featw[4][KNBR][6];
    __shared__ double sred[4][27];
    __shared__ float  tbuf[32];
    const int b  = blockIdx.x >> 6;
    const int qg = blockIdx.x & 63;
    const float* xb = x + (size_t)b * NPTS * 3;
    for (int i = threadIdx.x; i < NPTS; i += 256)
        pts[i] = stage4(xb[i*3+0], xb[i*3+1], xb[i*3+2]);
    __syncthreads();

    // ---- phase 0: select thresh = exact 20th-largest distance per query ----
    {
        const int qi = threadIdx.x >> 3;     // 0..31
        const int c  = threadIdx.x & 7;      // chunk 0..7
        const int n  = qg * 32 + qi;
        const float4 qc = pts[n];
        const float4 q = make_float4(0.5f*qc.x, 0.5f*qc.y, 0.5f*qc.z, qc.w);
        const int cbase = c * 256;
        const int rot   = (37 * c) & 255;    // bank-spread rotation (permutation)
        float bestv[KNBR];
#pragma unroll
        for (int j = 0; j < KNBR; ++j) bestv[j] = -__builtin_inff();
        // dense prefix: 64 candidates
        for (int m = 0; m < 64; m += 2) {
            const int j0 = (m + rot) & 255;
            const int j1 = (j0 + 1) & 255;
            float d0 = dist_eval(q, pts[cbase + j0]);
            float d1 = dist_eval(q, pts[cbase + j1]);
            pair_insert_sorted(bestv, fmaxf(d0, d1), fminf(d0, d1));
        }
        // cross-chunk floor L = max over the 8 chunk-threads of this query
        float L = bestv[KNBR-1];
        L = fmaxf(L, __shfl_xor(L, 1));
        L = fmaxf(L, __shfl_xor(L, 2));
        L = fmaxf(L, __shfl_xor(L, 4));
#pragma unroll
        for (int j = 0; j < KNBR; ++j) bestv[j] = fmaxf(bestv[j], L);
        float thresh = bestv[KNBR-1];
        // ring-buffered scan of remaining 192 candidates
        float r0 = -__builtin_inff(), r1 = r0, r2 = r0, r3 = r0;
        int rc = 0;
        for (int m = 64; m < 256; m += 2) {
            const int j0 = (m + rot) & 255;
            const int j1 = (j0 + 1) & 255;
            float d0 = dist_eval(q, pts[cbase + j0]);
            float d1 = dist_eval(q, pts[cbase + j1]);
            bool h0 = d0 > thresh;
            r3 = h0 ? r2 : r3; r2 = h0 ? r1 : r2; r1 = h0 ? r0 : r1; r0 = h0 ? d0 : r0;
            rc += h0 ? 1 : 0;
            bool h1 = d1 > thresh;
            r3 = h1 ? r2 : r3; r2 = h1 ? r1 : r2; r1 = h1 ? r0 : r1; r0 = h1 ? d1 : r0;
            rc += h1 ? 1 : 0;
            if (__any(rc >= 3)) {
                pair_insert_sorted(bestv, fmaxf(r0, r1), fminf(r0, r1));
                pair_insert_sorted(bestv, fmaxf(r2, r3), fminf(r2, r3));
                r0 = r1 = r2 = r3 = -__builtin_inff();
                rc = 0;
                thresh = bestv[KNBR-1];
            }
        }
        // final flush
        pair_insert_sorted(bestv, fmaxf(r0, r1), fminf(r0, r1));
        pair_insert_sorted(bestv, fmaxf(r2, r3), fminf(r2, r3));
        // register tree-merge across chunks (early-break pair inserts)
#pragma unroll
        for (int lev = 1; lev <= 4; lev <<= 1) {
            float orig[KNBR];
#pragma unroll
            for (int j = 0; j < KNBR; ++j) orig[j] = bestv[j];
            for (int i = 0; i < KNBR; i += 2) {
                float nb0 = __shfl_xor(orig[i],   lev);
                float nb1 = __shfl_xor(orig[i+1], lev);
                if (!__any(nb0 > bestv[KNBR-1])) break;
                pair_insert_sorted(bestv, nb0, nb1);
            }
        }
        if (c == 0) tbuf[qi] = bestv[KNBR-1];
    }
    __syncthreads();

    // ---- recovery: wave per 8 queries, ballot/prefix, ascending m ----
    const int wv = threadIdx.x >> 6, lane = threadIdx.x & 63;
    const unsigned long long below = (1ull << lane) - 1ull;
    for (int qi2 = 0; qi2 < 8; ++qi2) {
        const int p = wv * 8 + qi2;
        const int n = qg * 32 + p;
        const float4 qc = pts[n];
        const float4 q = make_float4(0.5f*qc.x, 0.5f*qc.y, 0.5f*qc.z, qc.w);
        const float th = tbuf[p];
        int cnt = 0;
        for (int it = 0; it < 32; ++it) {
            float d = dist_eval(q, pts[it*64 + lane]);
            const bool hit = (d >= th);
            unsigned long long mask = __ballot(hit);
            int pos = cnt + __popcll(mask & below);
            if (hit && pos < KNBR)
                idxl[p][pos] = (unsigned short)(it*64 + lane);
            cnt += __popcll(mask);
        }
    }
    __syncthreads();

    // ---- edge conv ----
    float cw[6];
#pragma unroll
    for (int c = 0; c < 6; ++c) cw[c] = conv_w[lane*6 + c];
    int pa_ = 0, pb_ = 0;
    if (lane >= 6 && lane < 27) {
        int t = lane - 6, a = 0;
        while (t >= 6 - a) { t -= 6 - a; ++a; }
        pa_ = a; pb_ = a + t;
    }
    double acc = 0.0;
    for (int i = 0; i < 8; ++i) {
        const int p = wv * 8 + i;
        const int nn = qg * 32 + p;
        const size_t bp = (size_t)b * NPTS + nn;
        const float4 Ci = pts[nn];
        const float xi0 = 0.5f*Ci.x, xi1 = 0.5f*Ci.y, xi2 = 0.5f*Ci.z;
        float f0=0,f1=0,f2=0,f3=0,f4=0,f5=0;
        if (lane < KNBR) {
            const float4 Cj = pts[idxl[p][lane]];
            f0 = 0.5f*(Cj.x - Ci.x);   // == fl(xj - xi) exactly
            f1 = 0.5f*(Cj.y - Ci.y);
            f2 = 0.5f*(Cj.z - Ci.z);
            f3 = xi0; f4 = xi1; f5 = xi2;
        }
        __syncthreads();
        if (lane < KNBR) {
            featw[wv][lane][0]=f0; featw[wv][lane][1]=f1; featw[wv][lane][2]=f2;
            featw[wv][lane][3]=f3; featw[wv][lane][4]=f4; featw[wv][lane][5]=f5;
        }
        __syncthreads();
        float vmax = -__builtin_inff(), vmin = __builtin_inff();
#pragma unroll
        for (int k = 0; k < KNBR; ++k) {
            float h = featw[wv][k][0] * cw[0];
            h = fmaf(featw[wv][k][1], cw[1], h);
            h = fmaf(featw[wv][k][2], cw[2], h);
            h = fmaf(featw[wv][k][3], cw[3], h);
            h = fmaf(featw[wv][k][4], cw[4], h);
            h = fmaf(featw[wv][k][5], cw[5], h);
            vmax = fmaxf(vmax, h); vmin = fminf(vmin, h);
        }
        maxh[bp*64 + lane] = vmax;
        minh[bp*64 + lane] = vmin;
        if (lane < 6) {
            double s = 0;
#pragma unroll
            for (int k = 0; k < KNBR; ++k) s += (double)featw[wv][k][lane];
            acc += s;
        } else if (lane < 27) {
            double s = 0;
#pragma unroll
            for (int k = 0; k < KNBR; ++k)
                s += (double)featw[wv][k][pa_] * (double)featw[wv][k][pb_];
            acc += s;
        }
    }
    if (lane < 27) sred[wv][lane] = acc;
    __syncthreads();
    if (threadIdx.x < 27) {
        double tot = sred[0][threadIdx.x] + sred[1][threadIdx.x]
                   + sred[2][threadIdx.x] + sred[3][threadIdx.x];
        atomicAdd(&S[threadIdx.x], tot);
    }
}

// ---------------------------------------------------------------------------
// MLP GEMM with in-kernel BN scale/shift derivation (identical double math
// per block -> identical floats).
// ---------------------------------------------------------------------------
template<int K, int N, bool SEL, bool POOLOUT, bool STATS0>
__global__ __launch_bounds__(256) void mlp_gemm(const float* __restrict__ A,
        const float* __restrict__ A2,
        const double* __restrict__ st_a, const double* __restrict__ st_b,
        const float* __restrict__ st_g, const float* __restrict__ st_bt,
        const float* __restrict__ cwm,
        const float* __restrict__ W, const float* __restrict__ bias,
        float* __restrict__ Y, double* __restrict__ sum, double* __restrict__ sq,
        float* __restrict__ pmax_g, float* __restrict__ pmin_g)
{
    constexpr int CPT = N / 16;                 // cols per thread (4 or 8)
    __shared__ float As[64 * 64];               // [k][row^swz], 16 KB
    __shared__ float Ws[64 * N];                // [k][n]
    __shared__ __align__(16) float s_scale[K], s_shift[K];
    const int tid = threadIdx.x;
    if (tid < K) {
        const int o = tid;
        if (STATS0) {
            double w[6];
#pragma unroll
            for (int c = 0; c < 6; ++c) w[c] = (double)cwm[o*6 + c];
            double mean = 0.0;
#pragma unroll
            for (int c = 0; c < 6; ++c) mean += w[c] * st_a[c];
            mean /= CONV_M;
            double ey2 = 0.0;
            int t = 6;
#pragma unroll
            for (int a = 0; a < 6; ++a)
#pragma unroll
                for (int b2 = a; b2 < 6; ++b2) {
                    double coef = (a == b2) ? 1.0 : 2.0;
                    ey2 += coef * w[a] * w[b2] * st_a[t];
                    ++t;
                }
            ey2 /= CONV_M;
            double var = ey2 - mean * mean;
            double sc = (double)st_g[o] / sqrt(var + BN_EPS);
            s_scale[o] = (float)sc;
            s_shift[o] = (float)((double)st_bt[o] - mean * sc);
        } else {
            double m = st_a[o] / ROW_M;
            double v = st_b[o] / ROW_M - m * m;
            double sc = (double)st_g[o] / sqrt(v + BN_EPS);
            s_scale[o] = (float)sc;
            s_shift[o] = (float)((double)st_bt[o] - m * sc);
        }
    }
    const int row0 = blockIdx.x * 64;
    const int ct = tid & 15, rt = tid >> 4;
    float acc[4][CPT];
#pragma unroll
    for (int rr = 0; rr < 4; ++rr)
#pragma unroll
        for (int cc = 0; cc < CPT; ++cc) acc[rr][cc] = bias[ct*CPT + cc];
    __syncthreads();

    for (int kk = 0; kk < K/64; ++kk) {
        if (kk) __syncthreads();
#pragma unroll
        for (int i = 0; i < 4; ++i) {
            const int f   = i * 256 + tid;
            const int k4  = f & 15;
            const int row = f >> 4;
            const int kg  = kk*64 + k4*4;
            float4 m = *(const float4*)(A + (size_t)(row0+row)*K + kg);
            const float4 s4 = *(const float4*)(&s_scale[kg]);
            const float4 h4 = *(const float4*)(&s_shift[kg]);
            if (SEL) {
                float4 m2 = *(const float4*)(A2 + (size_t)(row0+row)*K + kg);
                m.x = s4.x >= 0.f ? m.x : m2.x;
                m.y = s4.y >= 0.f ? m.y : m2.y;
                m.z = s4.z >= 0.f ? m.z : m2.z;
                m.w = s4.w >= 0.f ? m.w : m2.w;
            }
            const int rsw = row ^ ((k4 & 7) << 2);
            As[(k4*4+0)*64 + rsw] = lrelu(fmaf(s4.x, m.x, h4.x));
            As[(k4*4+1)*64 + rsw] = lrelu(fmaf(s4.y, m.y, h4.y));
            As[(k4*4+2)*64 + rsw] = lrelu(fmaf(s4.z, m.z, h4.z));
            As[(k4*4+3)*64 + rsw] = lrelu(fmaf(s4.w, m.w, h4.w));
        }
#pragma unroll
        for (int i = 0; i < N/16; ++i) {
            const int f    = i * 256 + tid;
            const int col4 = f & (N/4 - 1);
            const int krow = f / (N/4);
            *(float4*)(&Ws[krow*N + col4*4]) =
                *(const float4*)(W + (size_t)(kk*64 + krow)*N + col4*4);
        }
        __syncthreads();
#pragma unroll 4
        for (int k = 0; k < 64; ++k) {
            const int sw = ((k >> 2) & 7) << 2;
            const float4 a0 = *(const float4*)(&As[k*64 + ((rt*4) ^ sw)]);
            float a_[4] = {a0.x, a0.y, a0.z, a0.w};
            float w_[CPT];
#pragma unroll
            for (int v = 0; v < CPT/4; ++v) {
                const float4 wv4 = *(const float4*)(&Ws[k*N + ct*CPT + v*4]);
                w_[v*4+0] = wv4.x; w_[v*4+1] = wv4.y; w_[v*4+2] = wv4.z; w_[v*4+3] = wv4.w;
            }
#pragma unroll
            for (int rr = 0; rr < 4; ++rr)
#pragma unroll
                for (int cc = 0; cc < CPT; ++cc)
                    acc[rr][cc] = fmaf(a_[rr], w_[cc], acc[rr][cc]);
        }
    }
    if (!POOLOUT) {
#pragma unroll
        for (int rr = 0; rr < 4; ++rr) {
            float* yo = Y + (size_t)(row0 + rt*4 + rr)*N + ct*CPT;
#pragma unroll
            for (int v = 0; v < CPT/4; ++v)
                *(float4*)(yo + v*4) = make_float4(acc[rr][v*4+0], acc[rr][v*4+1],
                                                   acc[rr][v*4+2], acc[rr][v*4+3]);
        }
    }
    __syncthreads();                  // LDS dead; reuse As/Ws
    float* cr  = As;                  // [2N] column sum/sq partials
    float* pmx = As + 512;            // [16][N] per-rt max
    float* pmn = Ws;                  // [16][N] per-rt min
    if (tid < 2*N) cr[tid] = 0.f;
    if (POOLOUT) {
#pragma unroll
        for (int cc = 0; cc < CPT; ++cc) {
            float vmax = fmaxf(fmaxf(acc[0][cc], acc[1][cc]), fmaxf(acc[2][cc], acc[3][cc]));
            float vmin = fminf(fminf(acc[0][cc], acc[1][cc]), fminf(acc[2][cc], acc[3][cc]));
            pmx[rt*N + ct*CPT + cc] = vmax;
            pmn[rt*N + ct*CPT + cc] = vmin;
        }
    }
    __syncthreads();
#pragma unroll
    for (int cc = 0; cc < CPT; ++cc) {
        float s = acc[0][cc] + acc[1][cc] + acc[2][cc] + acc[3][cc];
        float q = fmaf(acc[0][cc], acc[0][cc], 0.f);
        q = fmaf(acc[1][cc], acc[1][cc], q);
        q = fmaf(acc[2][cc], acc[2][cc], q);
        q = fmaf(acc[3][cc], acc[3][cc], q);
        atomicAdd(&cr[ct*CPT + cc], s);
        atomicAdd(&cr[N + ct*CPT + cc], q);
    }
    float rm = 0.f, rn = 0.f;
    if (POOLOUT && tid < N) {
        rm = pmx[tid]; rn = pmn[tid];
#pragma unroll
        for (int r = 1; r < 16; ++r) {
            rm = fmaxf(rm, pmx[r*N + tid]);
            rn = fminf(rn, pmn[r*N + tid]);
        }
    }
    __syncthreads();
    if (tid < N) {
        atomicAdd(&sum[tid], (double)cr[tid]);
        atomicAdd(&sq[tid],  (double)cr[N + tid]);
        if (POOLOUT) {
            pmax_g[(size_t)blockIdx.x * N + tid] = rm;
            pmin_g[(size_t)blockIdx.x * N + tid] = rn;
        }
    }
}

// ---------------------------------------------------------------------------
// Fused BN3-derive + pool-finish + head. Block = batch b.
// ---------------------------------------------------------------------------
__global__ __launch_bounds__(256) void headpool_kernel(const float* __restrict__ pmax_g,
        const float* __restrict__ pmin_g,
        const double* __restrict__ sum3, const double* __restrict__ sq3,
        const float* __restrict__ g3, const float* __restrict__ bt3,
        const float* __restrict__ w4, const float* __restrict__ b4,
        const float* __restrict__ w5, const float* __restrict__ b5,
        float* __restrict__ out)
{
    __shared__ float xr[128];
    __shared__ float hh[512];
    const int b = blockIdx.x, t = threadIdx.x;
    if (t < 128) {
        double m_ = sum3[t] / ROW_M;
        double v_ = sq3[t] / ROW_M - m_ * m_;
        double scd = (double)g3[t] / sqrt(v_ + BN_EPS);
        const float sc = (float)scd;
        const float sh = (float)((double)bt3[t] - m_ * scd);
        const float* pm = pmax_g + (size_t)b * 32 * 128 + t;
        const float* pn = pmin_g + (size_t)b * 32 * 128 + t;
        float m = pm[0], n_ = pn[0];
#pragma unroll
        for (int r = 1; r < 32; ++r) {
            m  = fmaxf(m,  pm[r*128]);
            n_ = fminf(n_, pn[r*128]);
        }
        xr[t] = lrelu(sc >= 0.f ? fmaf(sc, m, sh) : fmaf(sc, n_, sh));
    }
    __syncthreads();
    float h0 = b4[t], h1 = b4[t + 256];
    for (int c = 0; c < 128; ++c) {
        float xc = xr[c];
        h0 = fmaf(xc, w4[c*512 + t],       h0);
        h1 = fmaf(xc, w4[c*512 + t + 256], h1);
    }
    hh[t]       = lrelu(h0);
    hh[t + 256] = lrelu(h1);
    __syncthreads();
    float acc = b5[t];
    for (int c = 0; c < 512; ++c)
        acc = fmaf(hh[c], w5[c*256 + t], acc);
    out[b*256 + t] = acc;
}

extern "C" void kernel_launch(void* const* d_in, const int* in_sizes, int n_in,
                              void* d_out, int out_size, void* d_ws, size_t ws_size,
                              hipStream_t stream)
{
    const float* x      = (const float*)d_in[0];
    const float* conv_w = (const float*)d_in[1];
    const float* conv_g = (const float*)d_in[2];
    const float* conv_b = (const float*)d_in[3];
    const float* w1  = (const float*)d_in[4];
    const float* b1  = (const float*)d_in[5];
    const float* g1  = (const float*)d_in[6];
    const float* bt1 = (const float*)d_in[7];
    const float* w2  = (const float*)d_in[8];
    const float* b2  = (const float*)d_in[9];
    const float* g2  = (const float*)d_in[10];
    const float* bt2 = (const float*)d_in[11];
    const float* w3  = (const float*)d_in[12];
    const float* b3  = (const float*)d_in[13];
    const float* g3  = (const float*)d_in[14];
    const float* bt3 = (const float*)d_in[15];
    const float* w4  = (const float*)d_in[16];
    const float* b4  = (const float*)d_in[17];
    const float* w5  = (const float*)d_in[18];
    const float* b5  = (const float*)d_in[19];

    char* p = (char*)d_ws;
    auto take = [&](size_t bytes) -> char* {
        char* r = p; p += (bytes + 255) & ~(size_t)255; return r;
    };
    double* S    = (double*)take(27 * 8);
    double* sum1 = (double*)take(64 * 8);
    double* sq1  = (double*)take(64 * 8);
    double* sum2 = (double*)take(128 * 8);
    double* sq2  = (double*)take(128 * 8);
    double* sum3 = (double*)take(128 * 8);
    double* sq3  = (double*)take(128 * 8);
    size_t zero_bytes = (size_t)(p - (char*)d_ws);
    float* pmaxg  = (float*)take((size_t)512 * 128 * 4);     // 256 KB
    float* pming  = (float*)take((size_t)512 * 128 * 4);     // 256 KB
    float* mm     = (float*)take((size_t)NROWS * 128 * 4);   // 16 MB
    float* maxh   = mm;
    float* minh   = mm + (size_t)NROWS * 64;
    float* y1     = (float*)take((size_t)NROWS * 64 * 4);    // 8 MB
    float* y2     = (float*)take((size_t)NROWS * 128 * 4);   // 16 MB

    hipMemsetAsync(d_ws, 0, zero_bytes, stream);
    knn_feat_kernel<<<dim3(NB * 64), dim3(256), 0, stream>>>(x, conv_w, maxh, minh, S);

    mlp_gemm<64,64,true,false,true>    <<<dim3(512), dim3(256), 0, stream>>>(
        maxh, minh, S, nullptr, conv_g, conv_b, conv_w, w1, b1, y1, sum1, sq1, nullptr, nullptr);
    mlp_gemm<64,128,false,false,false> <<<dim3(512), dim3(256), 0, stream>>>(
        y1, y1, sum1, sq1, g1, bt1, nullptr, w2, b2, y2, sum2, sq2, nullptr, nullptr);
    mlp_gemm<128,128,false,true,false> <<<dim3(512), dim3(256), 0, stream>>>(
        y2, y2, sum2, sq2, g2, bt2, nullptr, w3, b3, nullptr, sum3, sq3, pmaxg, pming);

    headpool_kernel<<<dim3(NB), dim3(256), 0, stream>>>(
        pmaxg, pming, sum3, sq3, g3, bt3, w4, b4, w5, b5, (float*)d_out);
}